// Round 1
// 539.866 us; speedup vs baseline: 1.0061x; 1.0061x over previous
//
#include <hip/hip_runtime.h>
#include <hip/hip_bf16.h>
#include <hip/hip_fp16.h>

#define F_DIM 128
#define N_RBF 20
#define CUTOFF 5.0f
#define PI_F 3.14159265358979323846f
#define NPB 4   // nodes per k_edge block

typedef float v2f __attribute__((ext_vector_type(2)));
typedef __attribute__((ext_vector_type(8))) short bf16x8;
typedef __attribute__((ext_vector_type(4))) float f32x4;
typedef _Float16 h2f __attribute__((ext_vector_type(2)));
typedef _Float16 f16x8 __attribute__((ext_vector_type(8)));

__device__ __forceinline__ unsigned int bf16_rtne(float f) {
    unsigned int u = __float_as_uint(f);
    u += 0x7fffu + ((u >> 16) & 1u);
    return u >> 16;
}
__device__ __forceinline__ unsigned int pack_bf2(float lo, float hi) {
    return bf16_rtne(lo) | (bf16_rtne(hi) << 16);
}
__device__ __forceinline__ float unpk_lo(unsigned int u) {
    return __uint_as_float(u << 16);
}
__device__ __forceinline__ float unpk_hi(unsigned int u) {
    return __uint_as_float(u & 0xffff0000u);
}
__device__ __forceinline__ float bf16_to_f(unsigned short s) {
    return __uint_as_float(((unsigned int)s) << 16);
}
__device__ __forceinline__ unsigned int pack_h2(float lo, float hi) {
    h2f h = (h2f){(_Float16)lo, (_Float16)hi};
    return __builtin_bit_cast(unsigned int, h);
}

// ---------------------------------------------------------------------------
__global__ __launch_bounds__(256) void k_rowptr(const int* __restrict__ idx_i,
                                                int* __restrict__ row_ptr, int N, int E) {
    int i = blockIdx.x * blockDim.x + threadIdx.x;
    if (i > N) return;
    if (i == N) { row_ptr[N] = E; return; }
    int lo = 0, hi = E;
    while (lo < hi) {
        int mid = (lo + hi) >> 1;
        if (idx_i[mid] < i) lo = mid + 1; else hi = mid;
    }
    row_ptr[i] = lo;
}

// ---------------------------------------------------------------------------
__global__ __launch_bounds__(256) void k_init(const int* __restrict__ Z,
                                              const float* __restrict__ emb,
                                              float* __restrict__ q,
                                              unsigned int* __restrict__ P,
                                              float* __restrict__ muD, int N) {
    int idx = blockIdx.x * blockDim.x + threadIdx.x;
    if (idx < N * F_DIM) {
        int n = idx >> 7, f = idx & 127;
        q[idx] = emb[Z[n] * F_DIM + f];
    }
    if (idx < N * 384) { P[idx] = 0u; muD[idx] = 0.f; }
}

// ---------------------------------------------------------------------------
// Weight prep: bf16-transposed MLP weights + f16 filter weights for MFMA.
// filtWt[l][c<384][k<24] = f16( k<20 ? filt_W[k][l*384+c]
//                             : k==20 ? filt_b[l*384+c] : 0 )
__global__ __launch_bounds__(256) void k_prep(const float* __restrict__ muxW,
                                              const float* __restrict__ W1,
                                              const float* __restrict__ W2,
                                              const float* __restrict__ iW1,
                                              const float* __restrict__ iW2,
                                              const float* __restrict__ filt_W,
                                              const float* __restrict__ filt_b,
                                              unsigned short* __restrict__ muxWt,
                                              unsigned short* __restrict__ W1t,
                                              unsigned short* __restrict__ W2t,
                                              unsigned short* __restrict__ iW1t,
                                              unsigned short* __restrict__ iW2t,
                                              unsigned short* __restrict__ filtWt) {
    int idx = blockIdx.x * 256 + threadIdx.x;
    if (idx < 98304) {                     // muxWt[l][c<256][k<128]
        int l = idx / 32768, rem = idx % 32768;
        int c = rem / 128, k = rem % 128;
        muxWt[idx] = (unsigned short)bf16_rtne(muxW[l * 32768 + k * 256 + c]);
    } else if (idx < 196608) {             // W1t[l][c<128][k<256]
        int i2 = idx - 98304;
        int l = i2 / 32768, rem = i2 % 32768;
        int c = rem / 256, k = rem % 256;
        W1t[i2] = (unsigned short)bf16_rtne(W1[l * 32768 + k * 128 + c]);
    } else if (idx < 344064) {             // W2t[l][c<384][k<128]
        int i2 = idx - 196608;
        int l = i2 / 49152, rem = i2 % 49152;
        int c = rem / 128, k = rem % 128;
        W2t[i2] = (unsigned short)bf16_rtne(W2[l * 49152 + k * 384 + c]);
    } else if (idx < 393216) {             // iW1t[l][c<128][k<128]
        int i2 = idx - 344064;
        int l = i2 / 16384, rem = i2 % 16384;
        int c = rem / 128, k = rem % 128;
        iW1t[i2] = (unsigned short)bf16_rtne(iW1[l * 16384 + k * 128 + c]);
    } else if (idx < 540672) {             // iW2t[l][c<384][k<128]
        int i2 = idx - 393216;
        int l = i2 / 49152, rem = i2 % 49152;
        int c = rem / 128, k = rem % 128;
        iW2t[i2] = (unsigned short)bf16_rtne(iW2[l * 49152 + k * 384 + c]);
    } else if (idx < 568320) {             // filtWt[l][c<384][k<24] f16
        int i2 = idx - 540672;
        int l = i2 / 9216, rem = i2 % 9216;
        int c = rem / 24, k = rem % 24;
        float v = 0.f;
        if (k < 20)       v = filt_W[k * 1152 + l * 384 + c];
        else if (k == 20) v = filt_b[l * 384 + c];
        _Float16 hv = (_Float16)v;
        filtWt[i2] = __builtin_bit_cast(unsigned short, hv);
    }
}

// ---------------------------------------------------------------------------
// Packed geometry record: 16 dwords (64 B): [0..2]=dir.xyz fp32; [3]=fcut;
// [4..15] = 24 f16: k0..19 = phi_k*fcut, k20 = fcut (bias channel), k21..23=0.
__global__ __launch_bounds__(256) void k_geom(const float* __restrict__ r,
                                              unsigned int* __restrict__ geom, int E) {
    int e = blockIdx.x * blockDim.x + threadIdx.x;
    if (e >= E) return;
    float x = r[e * 3], y = r[e * 3 + 1], z = r[e * 3 + 2];
    float d = sqrtf(x * x + y * y + z * z);
    float inv = 1.f / d;
    float fc = (d < CUTOFF) ? 0.5f * (__cosf(d * (PI_F / CUTOFF)) + 1.f) : 0.f;
    unsigned int* g = geom + (size_t)e * 16;
    g[0] = __float_as_uint(x * inv);
    g[1] = __float_as_uint(y * inv);
    g[2] = __float_as_uint(z * inv);
    g[3] = __float_as_uint(fc);
    const float delta = CUTOFF / (N_RBF - 1);
    const float coeff = -0.5f / (delta * delta);
    float ph[N_RBF];
#pragma unroll
    for (int k = 0; k < N_RBF; k++) {
        float t = d - k * delta;
        ph[k] = __expf(coeff * t * t) * fc;
    }
#pragma unroll
    for (int k = 0; k < N_RBF / 2; k++)
        g[4 + k] = pack_h2(ph[2 * k], ph[2 * k + 1]);
    g[14] = pack_h2(fc, 0.f);   // k20 = fcut (bias channel), k21 = 0
    g[15] = 0u;                 // k22, k23 = 0
}

// ---------------------------------------------------------------------------
// Node message MLP via MFMA (layer 0 only). 4 waves per 16-node tile.
__global__ __launch_bounds__(256) void k_node_mfma(
        const float* __restrict__ q,
        const unsigned short* __restrict__ iW1t,   // [128][128] bf16 (c,k)
        const float* __restrict__ b1,
        const unsigned short* __restrict__ iW2t,   // [384][128]
        const float* __restrict__ b2,
        unsigned int* __restrict__ P, int N) {
    __shared__ unsigned short A[16 * 136];
    __shared__ unsigned short Ah[16 * 136];
    __shared__ float Xs[16 * 396];
    int t = threadIdx.x;
    int w = t >> 6, l = t & 63, quad = l >> 4, c0 = l & 15;
    int n0 = blockIdx.x * 16;

#pragma unroll
    for (int i = 0; i < 4; i++) {
        int flat = i * 256 + t;
        int node = flat >> 6, cp = flat & 63;
        int gn = n0 + node;
        unsigned int v = 0u;
        if (gn < N) { const float* s = q + (size_t)gn * 128 + 2 * cp; v = pack_bf2(s[0], s[1]); }
        *(unsigned int*)&A[node * 136 + 2 * cp] = v;
    }
    __syncthreads();

    bf16x8 a1[4];
#pragma unroll
    for (int ks = 0; ks < 4; ks++)
        a1[ks] = *(const bf16x8*)&A[c0 * 136 + ks * 32 + quad * 8];
#pragma unroll
    for (int jj = 0; jj < 2; jj++) {
        int jg = 2 * w + jj;
        float bb = b1[16 * jg + c0];
        f32x4 acc = (f32x4){bb, bb, bb, bb};
#pragma unroll
        for (int ks = 0; ks < 4; ks++) {
            bf16x8 b = *(const bf16x8*)&iW1t[(16 * jg + c0) * 128 + ks * 32 + quad * 8];
            acc = __builtin_amdgcn_mfma_f32_16x16x32_bf16(a1[ks], b, acc, 0, 0, 0);
        }
#pragma unroll
        for (int r = 0; r < 4; r++) {
            float aa = acc[r];
            Ah[(quad * 4 + r) * 136 + 16 * jg + c0] =
                (unsigned short)bf16_rtne(aa / (1.f + __expf(-aa)));
        }
    }
    __syncthreads();

    bf16x8 a3[4];
#pragma unroll
    for (int ks = 0; ks < 4; ks++)
        a3[ks] = *(const bf16x8*)&Ah[c0 * 136 + ks * 32 + quad * 8];
#pragma unroll
    for (int jj = 0; jj < 6; jj++) {
        int jx = 6 * w + jj;
        float bb = b2[16 * jx + c0];
        f32x4 acc = (f32x4){bb, bb, bb, bb};
#pragma unroll
        for (int ks = 0; ks < 4; ks++) {
            bf16x8 b = *(const bf16x8*)&iW2t[(16 * jx + c0) * 128 + ks * 32 + quad * 8];
            acc = __builtin_amdgcn_mfma_f32_16x16x32_bf16(a3[ks], b, acc, 0, 0, 0);
        }
#pragma unroll
        for (int r = 0; r < 4; r++)
            Xs[(quad * 4 + r) * 396 + 16 * jx + c0] = acc[r];
    }
    __syncthreads();

    int n = t >> 4, fi = (t & 15) * 8;
    int gn = n0 + n;
    if (gn < N) {
        size_t base = (size_t)gn * 384;
        unsigned int d[8];
#pragma unroll
        for (int k = 0; k < 8; k++) {
            float x0 = Xs[n * 396 + fi + k];
            float x1 = Xs[n * 396 + 128 + fi + k];
            float x2 = Xs[n * 396 + 256 + fi + k];
            d[k] = pack_bf2(x0, x1);
            ((unsigned short*)&P[base + 256 + fi + k])[0] = (unsigned short)bf16_rtne(x2);
        }
        *(uint4*)&P[base + fi]     = make_uint4(d[0], d[1], d[2], d[3]);
        *(uint4*)&P[base + fi + 4] = make_uint4(d[4], d[5], d[6], d[7]);
    }
}

// ---------------------------------------------------------------------------
// A-frag loader for the filter MFMA: phi f16[24] at geom dwords 4..15,
// K padded to 32 (quad 3 = zeros).
__device__ __forceinline__ f16x8 load_phi_frag(const unsigned int* __restrict__ geom,
                                               int ts, int c0, int quad, int E) {
    int ea = ts + c0;
    if (ea >= E) ea = E - 1;          // clamp; pad rows are never aggregated
    f16x8 a = {};
    if (quad < 3)
        a = *(const f16x8*)&geom[(size_t)ea * 16 + 4 + quad * 4];
    return a;
}

// ---------------------------------------------------------------------------
// Edge aggregation. Filter GEMV now done by f16 MFMA per 16-edge tile into
// LDS Ws[16][384] f32 (bias*fcut baked in via the k=20 channel); the gather
// loop then reads w from LDS — removes 30 fdot2 + 10 phi-dword staging ops
// per edge per wave from the VALU path.
template <bool HAS_MU>
__global__ __launch_bounds__(256) void k_edge(
        const unsigned int* __restrict__ P,
        const unsigned int* __restrict__ geom,
        const int* __restrict__ idx_j,
        const int* __restrict__ row_ptr,
        const unsigned short* __restrict__ filtWt,  // [384][24] f16 (layer slice)
        float* __restrict__ q,
        float* __restrict__ muD, int N, int E) {
    constexpr int NT = HAS_MU ? 6 : 4;     // 16-col tiles per wave (24 or 16 total)
    constexpr int WS = 388;                // f32 row stride (384 + 4 pad)
    __shared__ float Ws[16 * WS];
    __shared__ float red[4][128];
    int t = threadIdx.x;
    int f = t & 127;
    int sub = __builtin_amdgcn_readfirstlane(t >> 7);
    int w = t >> 6, l = t & 63, quad = l >> 4, c0 = l & 15;

    // Preload B-frags (filter weights^T, f16) into registers: NT*4 VGPRs.
    f16x8 Bf[NT];
#pragma unroll
    for (int jj = 0; jj < NT; jj++) {
        int jx = NT * w + jj;
        f16x8 b = {};
        if (quad < 3)
            b = *(const f16x8*)&filtWt[(16 * jx + c0) * 24 + quad * 8];
        Bf[jj] = b;
    }

    int i0 = blockIdx.x * NPB;
    for (int nn = 0; nn < NPB; nn++) {
        int i = i0 + nn;
        if (i >= N) break;
        int rs = __builtin_amdgcn_readfirstlane(row_ptr[i]);
        int re = __builtin_amdgcn_readfirstlane(row_ptr[i + 1]);
        float dq = 0.f;
        v2f dm01 = (v2f){0.f, 0.f};
        float dm2 = 0.f;

        f16x8 a = load_phi_frag(geom, rs, c0, quad, E);
        for (int ts = rs; ts < re; ts += 16) {
            // --- filter MFMA phase: filters for 16 edges -> Ws ---
#pragma unroll
            for (int jj = 0; jj < NT; jj++) {
                int jx = NT * w + jj;
                f32x4 acc = (f32x4){0.f, 0.f, 0.f, 0.f};
                acc = __builtin_amdgcn_mfma_f32_16x16x32_f16(a, Bf[jj], acc, 0, 0, 0);
#pragma unroll
                for (int r = 0; r < 4; r++)
                    Ws[(quad * 4 + r) * WS + 16 * jx + c0] = acc[r];
            }
            __syncthreads();
            if (ts + 16 < re) a = load_phi_frag(geom, ts + 16, c0, quad, E);  // prefetch

            // --- aggregation phase ---
            int te = (re < ts + 16) ? re : ts + 16;
            for (int e = ts + sub; e < te; e += 2) {
                int j = __builtin_amdgcn_readfirstlane(idx_j[e]);
                const unsigned int* Pj = P + (size_t)j * 384;
                unsigned int A = Pj[f];                       // (xq|xr)
                unsigned int B = 0, C = 0;
                if (HAS_MU) { B = Pj[128 + f]; C = Pj[256 + f]; }

                const float* g = (const float*)(geom + (size_t)e * 16);
                float dirx = g[0], diry = g[1], dirz = g[2];

                int eloc = e - ts;
                float wq = Ws[eloc * WS + f];
                float wr = Ws[eloc * WS + 128 + f];

                float xq = unpk_lo(A), xr = unpk_hi(A);
                dq += wq * xq;
                float s_r = wr * xr;
                if (HAS_MU) {
                    float wm = Ws[eloc * WS + 256 + f];
                    float xm = unpk_lo(C);
                    float s_m = wm * xm;
                    dm01 += (v2f){s_r, s_r} * (v2f){dirx, diry} +
                            (v2f){s_m, s_m} * (v2f){unpk_lo(B), unpk_hi(B)};
                    dm2  += s_r * dirz + s_m * unpk_hi(C);
                } else {
                    dm01 += (v2f){s_r, s_r} * (v2f){dirx, diry};
                    dm2  += s_r * dirz;
                }
            }
            __syncthreads();
        }

        if (sub == 1) { red[0][f] = dq; red[1][f] = dm01.x; red[2][f] = dm01.y; red[3][f] = dm2; }
        __syncthreads();
        if (sub == 0) {
            dq += red[0][f];
            float d0 = dm01.x + red[1][f], d1 = dm01.y + red[2][f];
            dm2 += red[3][f];
            q[(size_t)i * 128 + f] += dq;
            size_t base = (size_t)i * 384;
            if (HAS_MU) {
                muD[base + f]       += d0;
                muD[base + 128 + f] += d1;
                muD[base + 256 + f] += dm2;
            } else {   // layer 0: mu starts at zero
                muD[base + f]       = d0;
                muD[base + 128 + f] = d1;
                muD[base + 256 + f] = dm2;
            }
        }
        __syncthreads();
    }
}

// ---------------------------------------------------------------------------
// Fused mixing(l) + node-message(l+1) kernel (unchanged).
__global__ __launch_bounds__(256) void k_mix_fused(
        float* __restrict__ q, float* __restrict__ mu,
        const unsigned short* __restrict__ muxWt,   // [256][128] bf16 (c,k)
        const unsigned short* __restrict__ W1t,     // [128][256]
        const unsigned short* __restrict__ W2t,     // [384][128]
        const float* __restrict__ b1,
        const float* __restrict__ b2,
        const unsigned short* __restrict__ niW1t,   // next-layer node W1t
        const float* __restrict__ nib1,
        const unsigned short* __restrict__ niW2t,   // next-layer node W2t
        const float* __restrict__ nib2,
        int has_node,
        unsigned int* __restrict__ P, int N) {
    __shared__ unsigned short A[16 * 264];          // [node][K=256+pad] bf16
    __shared__ unsigned short Wsp[3 * 16 * 136];    // mu_W bf16; reused as Ah
    __shared__ float Xs[16 * 396];
    __shared__ float Ss[16 * 140];
    int t = threadIdx.x;
    int w = t >> 6, l = t & 63, quad = l >> 4, c0 = l & 15;
    int n0 = blockIdx.x * 16;

#pragma unroll
    for (int i = 0; i < 4; i++) {
        int flat = i * 256 + t;
        int node = flat >> 6, cp = flat & 63;
        int gn = n0 + node;
        unsigned int v = 0u;
        if (gn < N) { const float* s = q + (size_t)gn * 128 + 2 * cp; v = pack_bf2(s[0], s[1]); }
        *(unsigned int*)&A[node * 264 + 2 * cp] = v;
    }

    f32x4 vn2[2], S[2];
#pragma unroll
    for (int jj = 0; jj < 2; jj++) { vn2[jj] = (f32x4){0,0,0,0}; S[jj] = (f32x4){0,0,0,0}; }

    for (int c = 0; c < 3; c++) {
#pragma unroll
        for (int i = 0; i < 4; i++) {
            int flat = i * 256 + t;
            int node = flat >> 6, cp = flat & 63;
            int gn = n0 + node;
            unsigned int v = 0u;
            if (gn < N) {
                const float* s = mu + (size_t)gn * 384 + c * 128 + 2 * cp;
                v = pack_bf2(s[0], s[1]);
            }
            *(unsigned int*)&A[node * 264 + 128 + 2 * cp] = v;
        }
        __syncthreads();
        bf16x8 af[4];
#pragma unroll
        for (int ks = 0; ks < 4; ks++)
            af[ks] = *(const bf16x8*)&A[c0 * 264 + 128 + ks * 32 + quad * 8];
#pragma unroll
        for (int jj = 0; jj < 2; jj++) {
            int jv = 2 * w + jj;
            f32x4 V = (f32x4){0,0,0,0}, Wm = (f32x4){0,0,0,0};
#pragma unroll
            for (int ks = 0; ks < 4; ks++) {
                bf16x8 bV = *(const bf16x8*)&muxWt[(16 * jv + c0) * 128 + ks * 32 + quad * 8];
                V = __builtin_amdgcn_mfma_f32_16x16x32_bf16(af[ks], bV, V, 0, 0, 0);
            }
#pragma unroll
            for (int ks = 0; ks < 4; ks++) {
                bf16x8 bW = *(const bf16x8*)&muxWt[(16 * (jv + 8) + c0) * 128 + ks * 32 + quad * 8];
                Wm = __builtin_amdgcn_mfma_f32_16x16x32_bf16(af[ks], bW, Wm, 0, 0, 0);
            }
            vn2[jj] += V * V;
            S[jj]   += V * Wm;
#pragma unroll
            for (int r = 0; r < 4; r++)
                Wsp[c * 2176 + (quad * 4 + r) * 136 + 16 * jv + c0] =
                    (unsigned short)bf16_rtne(Wm[r]);
        }
        __syncthreads();
    }

#pragma unroll
    for (int jj = 0; jj < 2; jj++) {
        int jv = 2 * w + jj;
#pragma unroll
        for (int r = 0; r < 4; r++)
            A[(quad * 4 + r) * 264 + 128 + 16 * jv + c0] =
                (unsigned short)bf16_rtne(sqrtf(vn2[jj][r] + 1e-8f));
    }
    __syncthreads();

    bf16x8 a2[8];
#pragma unroll
    for (int ks = 0; ks < 8; ks++)
        a2[ks] = *(const bf16x8*)&A[c0 * 264 + ks * 32 + quad * 8];
    {
        unsigned short htmp[2][4];
#pragma unroll
        for (int jj = 0; jj < 2; jj++) {
            int jg = 2 * w + jj;
            float bb = b1[16 * jg + c0];
            f32x4 acc = (f32x4){bb, bb, bb, bb};
#pragma unroll
            for (int ks = 0; ks < 8; ks++) {
                bf16x8 b = *(const bf16x8*)&W1t[(16 * jg + c0) * 256 + ks * 32 + quad * 8];
                acc = __builtin_amdgcn_mfma_f32_16x16x32_bf16(a2[ks], b, acc, 0, 0, 0);
            }
#pragma unroll
            for (int r = 0; r < 4; r++) {
                float aa = acc[r];
                htmp[jj][r] = (unsigned short)bf16_rtne(aa / (1.f + __expf(-aa)));
            }
        }
        __syncthreads();
#pragma unroll
        for (int jj = 0; jj < 2; jj++) {
            int jg = 2 * w + jj;
#pragma unroll
            for (int r = 0; r < 4; r++)
                A[(quad * 4 + r) * 264 + 128 + 16 * jg + c0] = htmp[jj][r];
        }
    }
    __syncthreads();

    bf16x8 a3[4];
#pragma unroll
    for (int ks = 0; ks < 4; ks++)
        a3[ks] = *(const bf16x8*)&A[c0 * 264 + 128 + ks * 32 + quad * 8];
#pragma unroll
    for (int jj = 0; jj < 6; jj++) {
        int jx = 6 * w + jj;
        float bb = b2[16 * jx + c0];
        f32x4 acc = (f32x4){bb, bb, bb, bb};
#pragma unroll
        for (int ks = 0; ks < 4; ks++) {
            bf16x8 b = *(const bf16x8*)&W2t[(16 * jx + c0) * 128 + ks * 32 + quad * 8];
            acc = __builtin_amdgcn_mfma_f32_16x16x32_bf16(a3[ks], b, acc, 0, 0, 0);
        }
#pragma unroll
        for (int r = 0; r < 4; r++)
            Xs[(quad * 4 + r) * 396 + 16 * jx + c0] = acc[r];
    }
#pragma unroll
    for (int jj = 0; jj < 2; jj++) {
        int jv = 2 * w + jj;
#pragma unroll
        for (int r = 0; r < 4; r++)
            Ss[(quad * 4 + r) * 140 + 16 * jv + c0] = S[jj][r];
    }
    __syncthreads();

    int n = t >> 4, fi = (t & 15) * 8;
    int gn = n0 + n;
    if (gn < N) {
        float* qp = q + (size_t)gn * 128 + fi;
        float qn[8];
#pragma unroll
        for (int k = 0; k < 8; k++) {
            qn[k] = qp[k] + Xs[n * 396 + fi + k] +
                    Xs[n * 396 + 256 + fi + k] * Ss[n * 140 + fi + k];
            qp[k] = qn[k];
        }
        unsigned int qd[4];
#pragma unroll
        for (int p = 0; p < 4; p++) qd[p] = pack_bf2(qn[2 * p], qn[2 * p + 1]);
        *(uint4*)&A[n * 264 + fi] = make_uint4(qd[0], qd[1], qd[2], qd[3]);

        size_t base = (size_t)gn * 384;
        float m[3][8];
#pragma unroll
        for (int c = 0; c < 3; c++) {
            float* mp = mu + base + c * 128 + fi;
#pragma unroll
            for (int k = 0; k < 8; k++) {
                m[c][k] = mp[k] + Xs[n * 396 + 128 + fi + k] *
                                  bf16_to_f(Wsp[c * 2176 + n * 136 + fi + k]);
                mp[k] = m[c][k];
            }
        }
        unsigned int d[8];
#pragma unroll
        for (int k = 0; k < 8; k++) {
            d[k] = pack_bf2(m[0][k], m[1][k]);
            ((unsigned short*)&P[base + 256 + fi + k])[1] = (unsigned short)bf16_rtne(m[2][k]);
        }
        *(uint4*)&P[base + 128 + fi]     = make_uint4(d[0], d[1], d[2], d[3]);
        *(uint4*)&P[base + 128 + fi + 4] = make_uint4(d[4], d[5], d[6], d[7]);
    }
    __syncthreads();

    if (has_node) {
        unsigned short* Ah = Wsp;
        bf16x8 a1[4];
#pragma unroll
        for (int ks = 0; ks < 4; ks++)
            a1[ks] = *(const bf16x8*)&A[c0 * 264 + ks * 32 + quad * 8];
#pragma unroll
        for (int jj = 0; jj < 2; jj++) {
            int jg = 2 * w + jj;
            float bb = nib1[16 * jg + c0];
            f32x4 acc = (f32x4){bb, bb, bb, bb};
#pragma unroll
            for (int ks = 0; ks < 4; ks++) {
                bf16x8 b = *(const bf16x8*)&niW1t[(16 * jg + c0) * 128 + ks * 32 + quad * 8];
                acc = __builtin_amdgcn_mfma_f32_16x16x32_bf16(a1[ks], b, acc, 0, 0, 0);
            }
#pragma unroll
            for (int r = 0; r < 4; r++) {
                float aa = acc[r];
                Ah[(quad * 4 + r) * 136 + 16 * jg + c0] =
                    (unsigned short)bf16_rtne(aa / (1.f + __expf(-aa)));
            }
        }
        __syncthreads();

        bf16x8 a4[4];
#pragma unroll
        for (int ks = 0; ks < 4; ks++)
            a4[ks] = *(const bf16x8*)&Ah[c0 * 136 + ks * 32 + quad * 8];
#pragma unroll
        for (int jj = 0; jj < 6; jj++) {
            int jx = 6 * w + jj;
            float bb = nib2[16 * jx + c0];
            f32x4 acc = (f32x4){bb, bb, bb, bb};
#pragma unroll
            for (int ks = 0; ks < 4; ks++) {
                bf16x8 b = *(const bf16x8*)&niW2t[(16 * jx + c0) * 128 + ks * 32 + quad * 8];
                acc = __builtin_amdgcn_mfma_f32_16x16x32_bf16(a4[ks], b, acc, 0, 0, 0);
            }
#pragma unroll
            for (int r = 0; r < 4; r++)
                Xs[(quad * 4 + r) * 396 + 16 * jx + c0] = acc[r];
        }
        __syncthreads();

        if (gn < N) {
            size_t base = (size_t)gn * 384;
            unsigned int d[8];
#pragma unroll
            for (int k = 0; k < 8; k++) {
                float x0 = Xs[n * 396 + fi + k];
                float x1 = Xs[n * 396 + 128 + fi + k];
                float x2 = Xs[n * 396 + 256 + fi + k];
                d[k] = pack_bf2(x0, x1);
                ((unsigned short*)&P[base + 256 + fi + k])[0] = (unsigned short)bf16_rtne(x2);
            }
            *(uint4*)&P[base + fi]     = make_uint4(d[0], d[1], d[2], d[3]);
            *(uint4*)&P[base + fi + 4] = make_uint4(d[4], d[5], d[6], d[7]);
        }
    }
}

// ---------------------------------------------------------------------------
extern "C" void kernel_launch(void* const* d_in, const int* in_sizes, int n_in,
                              void* d_out, int out_size, void* d_ws, size_t ws_size,
                              hipStream_t stream) {
    const int*   Z      = (const int*)d_in[0];
    const float* r_ij   = (const float*)d_in[1];
    const int*   idx_i  = (const int*)d_in[2];
    const int*   idx_j  = (const int*)d_in[3];
    const float* emb    = (const float*)d_in[4];
    const float* filt_W = (const float*)d_in[5];
    const float* filt_b = (const float*)d_in[6];
    const float* int_W1 = (const float*)d_in[7];
    const float* int_b1 = (const float*)d_in[8];
    const float* int_W2 = (const float*)d_in[9];
    const float* int_b2 = (const float*)d_in[10];
    const float* mix_W1 = (const float*)d_in[11];
    const float* mix_b1 = (const float*)d_in[12];
    const float* mix_W2 = (const float*)d_in[13];
    const float* mix_b2 = (const float*)d_in[14];
    const float* mux_W  = (const float*)d_in[15];

    int N = in_sizes[0];
    int E = in_sizes[2];

    float* q   = (float*)d_out;              // [N,128]  q state (fp32)
    float* muD = q + (size_t)N * 128;        // [N,3,128] mu state (fp32)

    unsigned int* geom = (unsigned int*)d_ws;                 // E*16 u32 (64 B/edge)
    unsigned int* P = geom + (size_t)E * 16;                  // N*384 u32
    int* row_ptr = (int*)(P + (size_t)N * 384);               // N+1
    uintptr_t waddr = (uintptr_t)(row_ptr + N + 1);
    waddr = (waddr + 15) & ~(uintptr_t)15;
    unsigned short* muxWt = (unsigned short*)waddr;   // 3*256*128
    unsigned short* W1t   = muxWt + 98304;            // 3*128*256
    unsigned short* W2t   = W1t + 98304;              // 3*384*128
    unsigned short* iW1t  = W2t + 147456;             // 3*128*128
    unsigned short* iW2t  = iW1t + 49152;             // 3*384*128
    unsigned short* filtWt = iW2t + 147456;           // 3*384*24 f16

    k_rowptr<<<(N + 1 + 255) / 256, 256, 0, stream>>>(idx_i, row_ptr, N, E);
    k_init<<<((size_t)N * 384 + 255) / 256, 256, 0, stream>>>(Z, emb, q, P, muD, N);
    k_geom<<<(E + 255) / 256, 256, 0, stream>>>(r_ij, geom, E);
    k_prep<<<2220, 256, 0, stream>>>(mux_W, mix_W1, mix_W2, int_W1, int_W2, filt_W, filt_b,
                                     muxWt, W1t, W2t, iW1t, iW2t, filtWt);

    int tiles = (N + 15) / 16;
    k_node_mfma<<<tiles, 256, 0, stream>>>(
        q, iW1t, int_b1, iW2t, int_b2, P, N);
    for (int l = 0; l < 3; l++) {
        if (l == 0)
            k_edge<false><<<(N + NPB - 1) / NPB, 256, 0, stream>>>(
                P, geom, idx_j, row_ptr, filtWt, q, muD, N, E);
        else
            k_edge<true><<<(N + NPB - 1) / NPB, 256, 0, stream>>>(
                P, geom, idx_j, row_ptr, filtWt + (size_t)l * 9216, q, muD, N, E);
        int nl = (l < 2) ? (l + 1) : 0;
        k_mix_fused<<<tiles, 256, 0, stream>>>(
            q, muD, muxWt + (size_t)l * 32768, W1t + (size_t)l * 32768,
            W2t + (size_t)l * 49152, mix_b1 + l * 128, mix_b2 + l * 384,
            iW1t + (size_t)nl * 16384, int_b1 + nl * 128,
            iW2t + (size_t)nl * 49152, int_b2 + nl * 384,
            (l < 2) ? 1 : 0, P, N);
    }
    // q in d_out; final mu (fp32 state) in muD = d_out mu region.
}